// Round 8
// baseline (294.380 us; speedup 1.0000x reference)
//
#include <hip/hip_runtime.h>

#define NN 50000
#define NE 800000
#define DIM 128
#define NB 196               // buckets: dst>>8, 256 nodes each
#define BCAP 4800            // bucket capacity (mean 4082, sigma 64 -> +11 sigma)
#define K1B 100              // K1 blocks, 8000 edges each

typedef __attribute__((ext_vector_type(8))) short bf16x8;
typedef __attribute__((ext_vector_type(8))) unsigned short u16x8;
typedef __attribute__((ext_vector_type(4))) float f32x4;

__device__ __forceinline__ unsigned short f2bf(float f) {
    unsigned int u = __builtin_bit_cast(unsigned int, f);
    u += 0x7fffu + ((u >> 16) & 1u);     // RNE
    return (unsigned short)(u >> 16);
}
__device__ __forceinline__ float bf2f(unsigned int lo16) {
    return __builtin_bit_cast(float, lo16 << 16);
}

// ---------------- prologue: f32->bf16 (x + 4 weights) + bcursor zero ----------------
__global__ __launch_bounds__(256)
void cvt_all_kernel(const float* __restrict__ x, unsigned short* __restrict__ xb,
                    const float* __restrict__ s0, const float* __restrict__ s1,
                    const float* __restrict__ s2, const float* __restrict__ s3,
                    unsigned short* __restrict__ d0, unsigned short* __restrict__ d1,
                    unsigned short* __restrict__ d2, unsigned short* __restrict__ d3,
                    int* __restrict__ bcursor) {
    const int blk = blockIdx.x;
    const float* s;
    unsigned short* d;
    int base;
    if (blk < 3125) {                       // x: 3125*256*8 = 6,400,000 exact
        s = x; d = xb;
        base = (blk * 256 + threadIdx.x) * 8;
    } else {                                // weights: 32 blocks, 8 per matrix
        int wb = blk - 3125;
        if (wb == 0 && threadIdx.x < NB) bcursor[threadIdx.x] = 0;
        int which = wb >> 3;
        s = which == 0 ? s0 : which == 1 ? s1 : which == 2 ? s2 : s3;
        d = which == 0 ? d0 : which == 1 ? d1 : which == 2 ? d2 : d3;
        base = ((wb & 7) * 256 + threadIdx.x) * 8;
    }
    float4 a = *(const float4*)(s + base);
    float4 b = *(const float4*)(s + base + 4);
    u16x8 r;
    r[0] = f2bf(a.x); r[1] = f2bf(a.y); r[2] = f2bf(a.z); r[3] = f2bf(a.w);
    r[4] = f2bf(b.x); r[5] = f2bf(b.y); r[6] = f2bf(b.z); r[7] = f2bf(b.w);
    *(u16x8*)(d + base) = r;
}

// ---------------- CSR build, deterministic-reservation bucketing ----------------
__global__ __launch_bounds__(256)
void bucket_kernel(const int* __restrict__ src, const int* __restrict__ dst,
                   int* __restrict__ bcursor, unsigned int* __restrict__ bedge) {
    __shared__ int hist[NB];
    __shared__ int base[NB];
    const int t = threadIdx.x;
    const int e0 = blockIdx.x * (NE / K1B);      // 8000 edges per block, exact
    const int e1 = e0 + (NE / K1B);
    for (int i = t; i < NB; i += 256) hist[i] = 0;
    __syncthreads();
    for (int e = e0 + t; e < e1; e += 256)
        atomicAdd(&hist[dst[e] >> 8], 1);
    __syncthreads();
    for (int i = t; i < NB; i += 256) {
        base[i] = atomicAdd(&bcursor[i], hist[i]);   // 100 ops/address total
        hist[i] = 0;                                  // reuse as local cursor
    }
    __syncthreads();
    for (int e = e0 + t; e < e1; e += 256) {
        int d = dst[e];
        int b = d >> 8;
        int pos = base[b] + atomicAdd(&hist[b], 1);
        if (pos < BCAP)
            bedge[(size_t)b * BCAP + pos] = ((unsigned int)(d & 255) << 16) | (unsigned int)src[e];
    }
}

// K2: per bucket -> per-node CSR slices (off2[n] = {start,end}) + eid
__global__ __launch_bounds__(256)
void bucket_csr_kernel(const int* __restrict__ bcursor,
                       const unsigned int* __restrict__ bedge,
                       int* __restrict__ eid, int2* __restrict__ off2) {
    __shared__ int cnt[256], start[256], run[256], s[256];
    const int b = blockIdx.x;
    const int t = threadIdx.x;
    int n = bcursor[b];
    if (n > BCAP) n = BCAP;
    cnt[t] = 0; run[t] = 0;
    __syncthreads();
    const unsigned int* be = bedge + (size_t)b * BCAP;
    for (int i = t; i < n; i += 256)
        atomicAdd(&cnt[be[i] >> 16], 1);
    __syncthreads();
    int v = cnt[t];
    s[t] = v;
#pragma unroll
    for (int d = 1; d < 256; d <<= 1) {
        __syncthreads();
        int tmp = (t >= d) ? s[t - d] : 0;
        __syncthreads();
        s[t] += tmp;
    }
    __syncthreads();
    int ex = s[t] - v;
    start[t] = ex;
    off2[b * 256 + t] = make_int2(b * BCAP + ex, b * BCAP + ex + v);
    __syncthreads();
    for (int i = t; i < n; i += 256) {
        unsigned int w = be[i];
        int node = w >> 16;
        int o = atomicAdd(&run[node], 1);
        eid[(size_t)b * BCAP + start[node] + o] = (int)(w & 0xffffu);
    }
}

// ---------------- fused gather + MFMA graph-conv ----------------
// block = 64 nodes x 128 outs. Phase 1: each wave gathers its 16 aggr rows
// (f32 accum -> bf16) into a swizzled LDS tile. Phase 2: MFMA over
// {aggr(LDS), x(global)} x {Wrel, Wroot} with W staged in LDS.
__global__ __launch_bounds__(256)
void conv_fused_kernel(const unsigned short* __restrict__ X,   // bf16 [NN][128]
                       const int2* __restrict__ off2,
                       const int* __restrict__ eid,
                       const unsigned short* __restrict__ W0,  // Wrel bf16 [128][128]
                       const unsigned short* __restrict__ W1,  // Wroot bf16
                       const float* __restrict__ bias,
                       unsigned short* __restrict__ Out) {
    __shared__ __align__(16) unsigned short Wl[16384];   // 32 KB, XOR-swizzled
    __shared__ __align__(16) unsigned short Ag[8192];    // 16 KB, 64 rows swizzled
    const int tid = threadIdx.x;
    const int wave = tid >> 6;
    const int lane = tid & 63;
    const int m0 = blockIdx.x * 64;
    const bool active = (m0 + wave * 16) < NN;   // strips all-or-nothing (50000%16==0)
    const int col = lane & 15;
    const int kgrp = lane >> 4;
    const int swzb = (col & 7) << 4;

    // ---- phase 1: gather this block's 64 aggr rows into LDS ----
    for (int r = 0; r < 16; ++r) {
        const int row = wave * 16 + r;           // local row 0..63
        const int node = m0 + row;
        float ax = 0.f, ay = 0.f;
        if (node < NN) {
            const int2 se = off2[node];
            int i = se.x;
            const int e = se.y;
            for (; i + 4 <= e; i += 4) {
                int n0 = eid[i], n1 = eid[i + 1], n2 = eid[i + 2], n3 = eid[i + 3];
                unsigned int v0 = *(const unsigned int*)(X + (size_t)n0 * DIM + lane * 2);
                unsigned int v1 = *(const unsigned int*)(X + (size_t)n1 * DIM + lane * 2);
                unsigned int v2 = *(const unsigned int*)(X + (size_t)n2 * DIM + lane * 2);
                unsigned int v3 = *(const unsigned int*)(X + (size_t)n3 * DIM + lane * 2);
                ax += (bf2f(v0 & 0xffffu) + bf2f(v1 & 0xffffu))
                    + (bf2f(v2 & 0xffffu) + bf2f(v3 & 0xffffu));
                ay += (bf2f(v0 >> 16) + bf2f(v1 >> 16)) + (bf2f(v2 >> 16) + bf2f(v3 >> 16));
            }
            for (; i < e; ++i) {
                int n = eid[i];
                unsigned int v = *(const unsigned int*)(X + (size_t)n * DIM + lane * 2);
                ax += bf2f(v & 0xffffu);
                ay += bf2f(v >> 16);
            }
        }
        unsigned int packed = ((unsigned int)f2bf(ay) << 16) | f2bf(ax);
        int byteoff = (row * 256 + lane * 4) ^ ((row & 7) << 4);
        *(unsigned int*)((char*)Ag + byteoff) = packed;
    }

    // ---- phase 2: MFMA ----
    f32x4 acc[8];
#pragma unroll
    for (int t = 0; t < 8; ++t) acc[t] = (f32x4){0.f, 0.f, 0.f, 0.f};

    const int arow = wave * 16 + col;            // local A row for this lane
    int growx = m0 + arow;                       // global x row (guarded)
    if (growx >= NN) growx = 0;

    for (int mat = 0; mat < 2; ++mat) {
        const unsigned short* W = mat ? W1 : W0;
        __syncthreads();
#pragma unroll
        for (int i = 0; i < 8; ++i) {
            int chunk = i * 256 + tid;
            int row = chunk >> 4;
            int b = (chunk * 16) ^ ((row & 7) << 4);
            *(uint4*)((char*)Wl + b) = *(const uint4*)(W + chunk * 8);
        }
        __syncthreads();
        if (active) {
#pragma unroll
            for (int ks = 0; ks < 4; ++ks) {
                bf16x8 afrag;
                if (mat == 0) {
                    int aoff = (arow * 256 + ks * 64 + kgrp * 16) ^ ((arow & 7) << 4);
                    afrag = *(const bf16x8*)((const char*)Ag + aoff);
                } else {
                    afrag = *(const bf16x8*)(X + (size_t)growx * DIM + ks * 32 + kgrp * 8);
                }
                const int kb = ks * 64 + kgrp * 16;
#pragma unroll
                for (int t = 0; t < 8; ++t) {
                    int n = t * 16 + col;
                    int byteoff = (n * 256 + kb) ^ swzb;
                    bf16x8 bfrag = *(const bf16x8*)((const char*)Wl + byteoff);
                    acc[t] = __builtin_amdgcn_mfma_f32_16x16x32_bf16(afrag, bfrag, acc[t], 0, 0, 0);
                }
            }
        }
    }
    if (active) {
        const int rgrp = lane >> 4;
#pragma unroll
        for (int t = 0; t < 8; ++t) {
            int n = t * 16 + col;
            float bv = bias[n];
#pragma unroll
            for (int j = 0; j < 4; ++j) {
                float v = fmaxf(acc[t][j] + bv, 0.f);
                int row = m0 + wave * 16 + rgrp * 4 + j;
                Out[(size_t)row * DIM + n] = f2bf(v);
            }
        }
    }
}

// ---------------- fused agent MLP (reads bf16 z, computes f32) ----------------
__global__ __launch_bounds__(256)
void mlp_kernel(const unsigned short* __restrict__ Z,
                const int* __restrict__ agent_idx,
                const float* __restrict__ Wp1, const float* __restrict__ bp1,
                const float* __restrict__ Wp2, const float* __restrict__ bp2,
                const float* __restrict__ Wp3, const float* __restrict__ bp3,
                float* __restrict__ Out) {
    __shared__ __align__(16) float sel[8][132];
    __shared__ __align__(16) float m1[8][132];
    __shared__ __align__(16) float m2[8][132];
    const int tid = threadIdx.x;
    const int ab = blockIdx.x * 8;

    {
        int al = tid >> 5;
        int c = (tid & 31) * 4;
        int node = agent_idx[ab + al];
        ushort4 v = *(const ushort4*)(Z + (size_t)node * DIM + c);
        sel[al][c + 0] = bf2f(v.x); sel[al][c + 1] = bf2f(v.y);
        sel[al][c + 2] = bf2f(v.z); sel[al][c + 3] = bf2f(v.w);
    }
    __syncthreads();
    {
        int o = tid & 127;
        int g = tid >> 7;
        float acc[4] = {0.f, 0.f, 0.f, 0.f};
        for (int k = 0; k < 128; k += 4) {
            float4 w = *(const float4*)(Wp1 + (size_t)o * 128 + k);
#pragma unroll
            for (int a = 0; a < 4; ++a) {
                int aa = g * 4 + a;
                acc[a] += w.x * sel[aa][k] + w.y * sel[aa][k + 1]
                        + w.z * sel[aa][k + 2] + w.w * sel[aa][k + 3];
            }
        }
        float b = bp1[o];
#pragma unroll
        for (int a = 0; a < 4; ++a) m1[g * 4 + a][o] = fmaxf(acc[a] + b, 0.f);
    }
    __syncthreads();
    {
        int o = tid & 127;
        int g = tid >> 7;
        float acc[4] = {0.f, 0.f, 0.f, 0.f};
        for (int k = 0; k < 128; k += 4) {
            float4 w = *(const float4*)(Wp2 + (size_t)o * 128 + k);
#pragma unroll
            for (int a = 0; a < 4; ++a) {
                int aa = g * 4 + a;
                acc[a] += w.x * m1[aa][k] + w.y * m1[aa][k + 1]
                        + w.z * m1[aa][k + 2] + w.w * m1[aa][k + 3];
            }
        }
        float b = bp2[o];
#pragma unroll
        for (int a = 0; a < 4; ++a) m2[g * 4 + a][o] = fmaxf(acc[a] + b, 0.f);
    }
    __syncthreads();
    {
#pragma unroll
        for (int oo = 0; oo < 2; ++oo) {
            int o = tid + oo * 256;
            float acc[8] = {0.f, 0.f, 0.f, 0.f, 0.f, 0.f, 0.f, 0.f};
            for (int k = 0; k < 128; k += 4) {
                float4 w = *(const float4*)(Wp3 + (size_t)o * 128 + k);
#pragma unroll
                for (int a = 0; a < 8; ++a) {
                    acc[a] += w.x * m2[a][k] + w.y * m2[a][k + 1]
                            + w.z * m2[a][k + 2] + w.w * m2[a][k + 3];
                }
            }
            float b = bp3[o];
#pragma unroll
            for (int a = 0; a < 8; ++a)
                Out[(size_t)(ab + a) * 512 + o] = acc[a] + b;
        }
    }
}

extern "C" void kernel_launch(void* const* d_in, const int* in_sizes, int n_in,
                              void* d_out, int out_size, void* d_ws, size_t ws_size,
                              hipStream_t stream) {
    const float* x       = (const float*)d_in[0];
    const int*   edge    = (const int*)d_in[1];   // JAX x64 disabled -> int32
    const int*   src     = edge;
    const int*   dst     = edge + NE;
    const int*   agent   = (const int*)d_in[2];
    const float* W1_rel  = (const float*)d_in[3];
    const float* b1_rel  = (const float*)d_in[4];
    const float* W1_root = (const float*)d_in[5];
    const float* W2_rel  = (const float*)d_in[6];
    const float* b2_rel  = (const float*)d_in[7];
    const float* W2_root = (const float*)d_in[8];
    const float* Wp1     = (const float*)d_in[9];
    const float* bp1     = (const float*)d_in[10];
    const float* Wp2     = (const float*)d_in[11];
    const float* bp2     = (const float*)d_in[12];
    const float* Wp3     = (const float*)d_in[13];
    const float* bp3     = (const float*)d_in[14];
    float* out = (float*)d_out;

    // workspace layout
    const size_t NNDIM = (size_t)NN * DIM;
    unsigned short* xb  = (unsigned short*)d_ws;     // 12.8 MB each
    unsigned short* hb  = xb + NNDIM;
    unsigned short* zb  = hb + NNDIM;
    unsigned short* w1r = zb + NNDIM;                // 4 x 32 KB
    unsigned short* w1o = w1r + 16384;
    unsigned short* w2r = w1o + 16384;
    unsigned short* w2o = w2r + 16384;
    int2* off2          = (int2*)(w2o + 16384);      // NB*256 int2
    int* bcursor        = (int*)(off2 + NB * 256);   // NB (+pad)
    unsigned int* bedge = (unsigned int*)(bcursor + 200);   // NB*BCAP u32
    int* eid            = (int*)(bedge + (size_t)NB * BCAP);

    const int conv_blocks = (NN + 63) / 64;   // 782

    // ---- prologue: bf16 conversion + bcursor zero, one dispatch ----
    cvt_all_kernel<<<3157, 256, 0, stream>>>(x, xb, W1_rel, W1_root, W2_rel, W2_root,
                                             w1r, w1o, w2r, w2o, bcursor);

    // ---- CSR build (bucketed, shared by both convs) ----
    bucket_kernel<<<K1B, 256, 0, stream>>>(src, dst, bcursor, bedge);
    bucket_csr_kernel<<<NB, 256, 0, stream>>>(bcursor, bedge, eid, off2);

    // ---- conv1 (fused gather+GEMM) ----
    conv_fused_kernel<<<conv_blocks, 256, 0, stream>>>(xb, off2, eid, w1r, w1o, b1_rel, hb);
    // ---- conv2 ----
    conv_fused_kernel<<<conv_blocks, 256, 0, stream>>>(hb, off2, eid, w2r, w2o, b2_rel, zb);
    // ---- agent MLP ----
    mlp_kernel<<<1024 / 8, 256, 0, stream>>>(zb, agent, Wp1, bp1, Wp2, bp2, Wp3, bp3, out);
}

// Round 9
// 153.374 us; speedup vs baseline: 1.9194x; 1.9194x over previous
//
#include <hip/hip_runtime.h>

#define NN 50000
#define NE 800000
#define DIM 128
#define NB 196               // buckets: dst>>8, 256 nodes each
#define BCAP 4800            // bucket capacity (mean 4082, sigma 64 -> +11 sigma)
#define K1B 100              // K1 blocks, 8000 edges each

typedef __attribute__((ext_vector_type(8))) short bf16x8;
typedef __attribute__((ext_vector_type(8))) unsigned short u16x8;
typedef __attribute__((ext_vector_type(4))) float f32x4;

__device__ __forceinline__ unsigned short f2bf(float f) {
    unsigned int u = __builtin_bit_cast(unsigned int, f);
    u += 0x7fffu + ((u >> 16) & 1u);     // RNE
    return (unsigned short)(u >> 16);
}
__device__ __forceinline__ float bf2f(unsigned int lo16) {
    return __builtin_bit_cast(float, lo16 << 16);
}

// ---------------- prologue: f32->bf16 (x + 4 weights) + bcursor zero ----------------
__global__ __launch_bounds__(256)
void cvt_all_kernel(const float* __restrict__ x, unsigned short* __restrict__ xb,
                    const float* __restrict__ s0, const float* __restrict__ s1,
                    const float* __restrict__ s2, const float* __restrict__ s3,
                    unsigned short* __restrict__ d0, unsigned short* __restrict__ d1,
                    unsigned short* __restrict__ d2, unsigned short* __restrict__ d3,
                    int* __restrict__ bcursor) {
    const int blk = blockIdx.x;
    const float* s;
    unsigned short* d;
    int base;
    if (blk < 3125) {                       // x: 3125*256*8 = 6,400,000 exact
        s = x; d = xb;
        base = (blk * 256 + threadIdx.x) * 8;
    } else {                                // weights: 32 blocks, 8 per matrix
        int wb = blk - 3125;
        if (wb == 0 && threadIdx.x < NB) bcursor[threadIdx.x] = 0;
        int which = wb >> 3;
        s = which == 0 ? s0 : which == 1 ? s1 : which == 2 ? s2 : s3;
        d = which == 0 ? d0 : which == 1 ? d1 : which == 2 ? d2 : d3;
        base = ((wb & 7) * 256 + threadIdx.x) * 8;
    }
    float4 a = *(const float4*)(s + base);
    float4 b = *(const float4*)(s + base + 4);
    u16x8 r;
    r[0] = f2bf(a.x); r[1] = f2bf(a.y); r[2] = f2bf(a.z); r[3] = f2bf(a.w);
    r[4] = f2bf(b.x); r[5] = f2bf(b.y); r[6] = f2bf(b.z); r[7] = f2bf(b.w);
    *(u16x8*)(d + base) = r;
}

// ---------------- CSR build, deterministic-reservation bucketing ----------------
__global__ __launch_bounds__(256)
void bucket_kernel(const int* __restrict__ src, const int* __restrict__ dst,
                   int* __restrict__ bcursor, unsigned int* __restrict__ bedge) {
    __shared__ int hist[NB];
    __shared__ int base[NB];
    const int t = threadIdx.x;
    const int e0 = blockIdx.x * (NE / K1B);      // 8000 edges per block, exact
    const int e1 = e0 + (NE / K1B);
    for (int i = t; i < NB; i += 256) hist[i] = 0;
    __syncthreads();
    for (int e = e0 + t; e < e1; e += 256)
        atomicAdd(&hist[dst[e] >> 8], 1);
    __syncthreads();
    for (int i = t; i < NB; i += 256) {
        base[i] = atomicAdd(&bcursor[i], hist[i]);   // 100 ops/address total
        hist[i] = 0;                                  // reuse as local cursor
    }
    __syncthreads();
    for (int e = e0 + t; e < e1; e += 256) {
        int d = dst[e];
        int b = d >> 8;
        int pos = base[b] + atomicAdd(&hist[b], 1);
        if (pos < BCAP)
            bedge[(size_t)b * BCAP + pos] = ((unsigned int)(d & 255) << 16) | (unsigned int)src[e];
    }
}

// K2: per bucket -> per-node CSR slices (off2[n] = {start,end}) + eid
__global__ __launch_bounds__(256)
void bucket_csr_kernel(const int* __restrict__ bcursor,
                       const unsigned int* __restrict__ bedge,
                       int* __restrict__ eid, int2* __restrict__ off2) {
    __shared__ int cnt[256], start[256], run[256], s[256];
    const int b = blockIdx.x;
    const int t = threadIdx.x;
    int n = bcursor[b];
    if (n > BCAP) n = BCAP;
    cnt[t] = 0; run[t] = 0;
    __syncthreads();
    const unsigned int* be = bedge + (size_t)b * BCAP;
    for (int i = t; i < n; i += 256)
        atomicAdd(&cnt[be[i] >> 16], 1);
    __syncthreads();
    int v = cnt[t];
    s[t] = v;
#pragma unroll
    for (int d = 1; d < 256; d <<= 1) {
        __syncthreads();
        int tmp = (t >= d) ? s[t - d] : 0;
        __syncthreads();
        s[t] += tmp;
    }
    __syncthreads();
    int ex = s[t] - v;
    start[t] = ex;
    off2[b * 256 + t] = make_int2(b * BCAP + ex, b * BCAP + ex + v);
    __syncthreads();
    for (int i = t; i < n; i += 256) {
        unsigned int w = be[i];
        int node = w >> 16;
        int o = atomicAdd(&run[node], 1);
        eid[(size_t)b * BCAP + start[node] + o] = (int)(w & 0xffffu);
    }
}

// ---------------- wide bf16 gather-aggregate ----------------
// one wave per node; 4 groups of 16 lanes stream interleaved neighbors,
// each lane reads a 16B chunk (8 bf16); butterfly-combine groups at the end
__global__ __launch_bounds__(256)
void gather_bf16_kernel(const unsigned short* __restrict__ x,
                        const int2* __restrict__ off2,
                        const int* __restrict__ eid,
                        unsigned short* __restrict__ aggr) {
    const int node = blockIdx.x * 4 + (threadIdx.x >> 6);
    const int lane = threadIdx.x & 63;
    const int grp  = lane >> 4;        // 0..3: neighbor stream
    const int c16  = lane & 15;        // 16B chunk within the 256B row
    const int2 se = off2[node];
    const int s = se.x, e = se.y;
    const unsigned short* __restrict__ xc = x + c16 * 8;
    float acc[8] = {0.f, 0.f, 0.f, 0.f, 0.f, 0.f, 0.f, 0.f};
    int i = s + grp;
    for (; i + 4 < e; i += 8) {                  // 2 outstanding 16B loads/lane
        int n0 = eid[i];
        int n1 = eid[i + 4];
        u16x8 v0 = *(const u16x8*)(xc + (size_t)n0 * DIM);
        u16x8 v1 = *(const u16x8*)(xc + (size_t)n1 * DIM);
#pragma unroll
        for (int j = 0; j < 8; ++j)
            acc[j] += bf2f((unsigned short)v0[j]) + bf2f((unsigned short)v1[j]);
    }
    if (i < e) {
        int n = eid[i];
        u16x8 v = *(const u16x8*)(xc + (size_t)n * DIM);
#pragma unroll
        for (int j = 0; j < 8; ++j) acc[j] += bf2f((unsigned short)v[j]);
    }
    // combine the 4 groups (same columns at same c16) across lane bits 4,5
#pragma unroll
    for (int j = 0; j < 8; ++j) {
        acc[j] += __shfl_xor(acc[j], 16, 64);
        acc[j] += __shfl_xor(acc[j], 32, 64);
    }
    if (grp == 0) {
        u16x8 r;
#pragma unroll
        for (int j = 0; j < 8; ++j) r[j] = f2bf(acc[j]);
        *(u16x8*)(aggr + (size_t)node * DIM + c16 * 8) = r;
    }
}

// ---------------- MFMA graph-conv ----------------
__global__ __launch_bounds__(256)
void conv_mfma_kernel(const unsigned short* __restrict__ A0,  // aggr bf16 [NN][128]
                      const unsigned short* __restrict__ A1,  // x/h bf16
                      const unsigned short* __restrict__ W0,  // Wrel bf16 [128][128]
                      const unsigned short* __restrict__ W1,  // Wroot bf16
                      const float* __restrict__ bias,
                      unsigned short* __restrict__ Out) {
    __shared__ __align__(16) unsigned short Wl[16384];   // 32 KB, XOR-swizzled
    const int tid = threadIdx.x;
    const int wave = tid >> 6;
    const int lane = tid & 63;
    const int m0 = blockIdx.x * 64 + wave * 16;
    const bool active = m0 < NN;
    const int col = lane & 15;
    const int kgrp = lane >> 4;
    const int swz = (col & 7) << 4;

    f32x4 acc[8];
#pragma unroll
    for (int t = 0; t < 8; ++t) acc[t] = (f32x4){0.f, 0.f, 0.f, 0.f};

    for (int mat = 0; mat < 2; ++mat) {
        const unsigned short* A = mat ? A1 : A0;
        const unsigned short* W = mat ? W1 : W0;
        __syncthreads();
#pragma unroll
        for (int i = 0; i < 8; ++i) {
            int chunk = i * 256 + tid;
            int row = chunk >> 4;
            int b = (chunk * 16) ^ ((row & 7) << 4);
            *(uint4*)((char*)Wl + b) = *(const uint4*)(W + chunk * 8);
        }
        __syncthreads();
        if (active) {
            const int arow = m0 + col;
#pragma unroll
            for (int ks = 0; ks < 4; ++ks) {
                bf16x8 afrag = *(const bf16x8*)(A + (size_t)arow * DIM + ks * 32 + kgrp * 8);
                const int kb = ks * 64 + kgrp * 16;
#pragma unroll
                for (int t = 0; t < 8; ++t) {
                    int n = t * 16 + col;
                    int byteoff = (n * 256 + kb) ^ swz;
                    bf16x8 bfrag = *(const bf16x8*)((const char*)Wl + byteoff);
                    acc[t] = __builtin_amdgcn_mfma_f32_16x16x32_bf16(afrag, bfrag, acc[t], 0, 0, 0);
                }
            }
        }
    }
    if (active) {
        const int rgrp = lane >> 4;
#pragma unroll
        for (int t = 0; t < 8; ++t) {
            int n = t * 16 + col;
            float bv = bias[n];
#pragma unroll
            for (int j = 0; j < 4; ++j) {
                float v = fmaxf(acc[t][j] + bv, 0.f);
                int row = m0 + rgrp * 4 + j;
                Out[(size_t)row * DIM + n] = f2bf(v);
            }
        }
    }
}

// ---------------- fused agent MLP (reads bf16 z, computes f32) ----------------
__global__ __launch_bounds__(256)
void mlp_kernel(const unsigned short* __restrict__ Z,
                const int* __restrict__ agent_idx,
                const float* __restrict__ Wp1, const float* __restrict__ bp1,
                const float* __restrict__ Wp2, const float* __restrict__ bp2,
                const float* __restrict__ Wp3, const float* __restrict__ bp3,
                float* __restrict__ Out) {
    __shared__ __align__(16) float sel[8][132];
    __shared__ __align__(16) float m1[8][132];
    __shared__ __align__(16) float m2[8][132];
    const int tid = threadIdx.x;
    const int ab = blockIdx.x * 8;

    {
        int al = tid >> 5;
        int c = (tid & 31) * 4;
        int node = agent_idx[ab + al];
        ushort4 v = *(const ushort4*)(Z + (size_t)node * DIM + c);
        sel[al][c + 0] = bf2f(v.x); sel[al][c + 1] = bf2f(v.y);
        sel[al][c + 2] = bf2f(v.z); sel[al][c + 3] = bf2f(v.w);
    }
    __syncthreads();
    {
        int o = tid & 127;
        int g = tid >> 7;
        float acc[4] = {0.f, 0.f, 0.f, 0.f};
        for (int k = 0; k < 128; k += 4) {
            float4 w = *(const float4*)(Wp1 + (size_t)o * 128 + k);
#pragma unroll
            for (int a = 0; a < 4; ++a) {
                int aa = g * 4 + a;
                acc[a] += w.x * sel[aa][k] + w.y * sel[aa][k + 1]
                        + w.z * sel[aa][k + 2] + w.w * sel[aa][k + 3];
            }
        }
        float b = bp1[o];
#pragma unroll
        for (int a = 0; a < 4; ++a) m1[g * 4 + a][o] = fmaxf(acc[a] + b, 0.f);
    }
    __syncthreads();
    {
        int o = tid & 127;
        int g = tid >> 7;
        float acc[4] = {0.f, 0.f, 0.f, 0.f};
        for (int k = 0; k < 128; k += 4) {
            float4 w = *(const float4*)(Wp2 + (size_t)o * 128 + k);
#pragma unroll
            for (int a = 0; a < 4; ++a) {
                int aa = g * 4 + a;
                acc[a] += w.x * m1[aa][k] + w.y * m1[aa][k + 1]
                        + w.z * m1[aa][k + 2] + w.w * m1[aa][k + 3];
            }
        }
        float b = bp2[o];
#pragma unroll
        for (int a = 0; a < 4; ++a) m2[g * 4 + a][o] = fmaxf(acc[a] + b, 0.f);
    }
    __syncthreads();
    {
#pragma unroll
        for (int oo = 0; oo < 2; ++oo) {
            int o = tid + oo * 256;
            float acc[8] = {0.f, 0.f, 0.f, 0.f, 0.f, 0.f, 0.f, 0.f};
            for (int k = 0; k < 128; k += 4) {
                float4 w = *(const float4*)(Wp3 + (size_t)o * 128 + k);
#pragma unroll
                for (int a = 0; a < 8; ++a) {
                    acc[a] += w.x * m2[a][k] + w.y * m2[a][k + 1]
                            + w.z * m2[a][k + 2] + w.w * m2[a][k + 3];
                }
            }
            float b = bp3[o];
#pragma unroll
            for (int a = 0; a < 8; ++a)
                Out[(size_t)(ab + a) * 512 + o] = acc[a] + b;
        }
    }
}

extern "C" void kernel_launch(void* const* d_in, const int* in_sizes, int n_in,
                              void* d_out, int out_size, void* d_ws, size_t ws_size,
                              hipStream_t stream) {
    const float* x       = (const float*)d_in[0];
    const int*   edge    = (const int*)d_in[1];   // JAX x64 disabled -> int32
    const int*   src     = edge;
    const int*   dst     = edge + NE;
    const int*   agent   = (const int*)d_in[2];
    const float* W1_rel  = (const float*)d_in[3];
    const float* b1_rel  = (const float*)d_in[4];
    const float* W1_root = (const float*)d_in[5];
    const float* W2_rel  = (const float*)d_in[6];
    const float* b2_rel  = (const float*)d_in[7];
    const float* W2_root = (const float*)d_in[8];
    const float* Wp1     = (const float*)d_in[9];
    const float* bp1     = (const float*)d_in[10];
    const float* Wp2     = (const float*)d_in[11];
    const float* bp2     = (const float*)d_in[12];
    const float* Wp3     = (const float*)d_in[13];
    const float* bp3     = (const float*)d_in[14];
    float* out = (float*)d_out;

    // workspace layout
    const size_t NNDIM = (size_t)NN * DIM;
    unsigned short* xb  = (unsigned short*)d_ws;     // 12.8 MB each
    unsigned short* ab  = xb + NNDIM;                // aggr (reused by both convs)
    unsigned short* hb  = ab + NNDIM;
    unsigned short* zb  = hb + NNDIM;
    unsigned short* w1r = zb + NNDIM;                // 4 x 32 KB
    unsigned short* w1o = w1r + 16384;
    unsigned short* w2r = w1o + 16384;
    unsigned short* w2o = w2r + 16384;
    int2* off2          = (int2*)(w2o + 16384);      // NB*256 int2
    int* bcursor        = (int*)(off2 + NB * 256);   // NB (+pad)
    unsigned int* bedge = (unsigned int*)(bcursor + 200);   // NB*BCAP u32
    int* eid            = (int*)(bedge + (size_t)NB * BCAP);

    const int conv_blocks = (NN + 63) / 64;   // 782
    const int gather_blocks = NN / 4;         // 12500

    // ---- prologue: bf16 conversion + bcursor zero, one dispatch ----
    cvt_all_kernel<<<3157, 256, 0, stream>>>(x, xb, W1_rel, W1_root, W2_rel, W2_root,
                                             w1r, w1o, w2r, w2o, bcursor);

    // ---- CSR build (bucketed, shared by both convs) ----
    bucket_kernel<<<K1B, 256, 0, stream>>>(src, dst, bcursor, bedge);
    bucket_csr_kernel<<<NB, 256, 0, stream>>>(bcursor, bedge, eid, off2);

    // ---- conv1 ----
    gather_bf16_kernel<<<gather_blocks, 256, 0, stream>>>(xb, off2, eid, ab);
    conv_mfma_kernel<<<conv_blocks, 256, 0, stream>>>(ab, xb, w1r, w1o, b1_rel, hb);
    // ---- conv2 ----
    gather_bf16_kernel<<<gather_blocks, 256, 0, stream>>>(hb, off2, eid, ab);
    conv_mfma_kernel<<<conv_blocks, 256, 0, stream>>>(ab, hb, w2r, w2o, b2_rel, zb);
    // ---- agent MLP ----
    mlp_kernel<<<1024 / 8, 256, 0, stream>>>(zb, agent, Wp1, bp1, Wp2, bp2, Wp3, bp3, out);
}